// Round 8
// baseline (1250.709 us; speedup 1.0000x reference)
//
#include <hip/hip_runtime.h>
#include <hip/hip_fp16.h>

#define N_IN_SZ   400000
#define N_OUT_SZ  200000
#define K_OFF     27
#define R_RULES   200000
#define NC        32
#define TOTAL_E   (K_OFF * R_RULES)     // 5,400,000

// chunk = o >> 7 (128 outputs per chunk), chunk-major buckets: b = chunk*27 + k
#define CH_SHIFT  7
#define CH_ROWS   128
#define NCHUNK    1563                   // ceil(200000/128)
#define NB        (NCHUNK * K_OFF)       // 42,201
#define NB_PAD    43008                  // 42 * 1024
#define N_CNT4    (NB_PAD / 4)           // 10,752
#define NSCANBLK  42

#define HIST_BLK  8
#define RPH       25000                  // rules per hist/fill block

typedef unsigned int u32;
typedef unsigned long long u64;

// ---------------- ws layout (bytes) — identical footprint to R7 (known to fit)
#define SORT_OFF    0ull                                   // u32[TOTAL_E] = 21,600,000
#define CNT_OFF     21600000ull
#define START_OFF   (CNT_OFF   + (u64)NB_PAD * 4)
#define CURSOR_OFF  (START_OFF + (u64)NB_PAD * 4)
#define BSUM_OFF    (CURSOR_OFF + (u64)NB_PAD * 4)
#define BOFF_OFF    (BSUM_OFF + 256ull)
#define WS_NEW_NEEDED (BOFF_OFF + 256ull)                  // 22,116,608

// fallback (R4) ws need
#define ACC_WORDS  (N_OUT_SZ * 16)
#define WS_F16_NEEDED  ((size_t)ACC_WORDS * 4)

// ===========================================================================
// sort pipeline: bucket = chunk*27 + k. LDS-hist; two-phase fill.
// entry = (o&127)<<24 | k<<19 | irow
// ===========================================================================
__global__ __launch_bounds__(256) void zero_cnt_kernel(uint4* __restrict__ cnt4)
{
    int i = blockIdx.x * 256 + threadIdx.x;
    if (i < N_CNT4) cnt4[i] = make_uint4(0, 0, 0, 0);
}

__global__ __launch_bounds__(256) void hist_kernel(
    const int* __restrict__ out_idx, u32* __restrict__ cnt)
{
    __shared__ u32 lh[NCHUNK];
    for (int t = threadIdx.x; t < NCHUNK; t += 256) lh[t] = 0;
    __syncthreads();
    const int k    = blockIdx.y;
    const int base = blockIdx.x * RPH;
    for (int r = base + threadIdx.x; r < base + RPH; r += 256)
        atomicAdd(&lh[((u32)out_idx[(size_t)k * R_RULES + r]) >> CH_SHIFT], 1u);
    __syncthreads();
    for (int t = threadIdx.x; t < NCHUNK; t += 256) {
        u32 v = lh[t];
        if (v) atomicAdd(&cnt[(u32)t * K_OFF + (u32)k], v);
    }
}

__global__ __launch_bounds__(256) void blocksum_kernel(
    const uint4* __restrict__ cnt4, u32* __restrict__ bsum)
{
    int i4 = blockIdx.x * 256 + threadIdx.x;
    u32 s = 0;
    if (i4 < N_CNT4) {
        uint4 c = cnt4[i4];
        s = c.x + c.y + c.z + c.w;
    }
    int lane = threadIdx.x & 63;
#pragma unroll
    for (int off = 32; off > 0; off >>= 1)
        s += __shfl_down(s, off);
    __shared__ u32 ws[4];
    int wid = threadIdx.x >> 6;
    if (lane == 0) ws[wid] = s;
    __syncthreads();
    if (threadIdx.x == 0)
        bsum[blockIdx.x] = ws[0] + ws[1] + ws[2] + ws[3];
}

__global__ __launch_bounds__(256) void scanblk_kernel(
    const u32* __restrict__ bsum, u32* __restrict__ boff)
{
    __shared__ u32 lds[NSCANBLK];
    int t = threadIdx.x;
    if (t < NSCANBLK) lds[t] = bsum[t];
    __syncthreads();
    if (t == 0) {
        u32 run = 0;
        for (int i = 0; i < NSCANBLK; ++i) { u32 v = lds[i]; lds[i] = run; run += v; }
    }
    __syncthreads();
    if (t < NSCANBLK) boff[t] = lds[t];
}

__global__ __launch_bounds__(256) void scanwrite_kernel(
    const uint4* __restrict__ cnt4, const u32* __restrict__ boff,
    uint4* __restrict__ start4, uint4* __restrict__ cursor4)
{
    int i4 = blockIdx.x * 256 + threadIdx.x;
    uint4 c = (i4 < N_CNT4) ? cnt4[i4] : make_uint4(0, 0, 0, 0);
    u32 lsum = c.x + c.y + c.z + c.w;
    u32 s = lsum;
    int lane = threadIdx.x & 63;
#pragma unroll
    for (int off = 1; off < 64; off <<= 1) {
        u32 v = __shfl_up(s, off);
        if (lane >= off) s += v;
    }
    __shared__ u32 wsum[4], wbase[4];
    int wid = threadIdx.x >> 6;
    if (lane == 63) wsum[wid] = s;
    __syncthreads();
    if (threadIdx.x == 0) {
        u32 run = 0;
        for (int w = 0; w < 4; ++w) { wbase[w] = run; run += wsum[w]; }
    }
    __syncthreads();
    u32 base = boff[blockIdx.x] + wbase[wid] + (s - lsum);
    if (i4 < N_CNT4) {
        uint4 st;
        st.x = base;
        st.y = st.x + c.x;
        st.z = st.y + c.y;
        st.w = st.z + c.z;
        start4[i4]  = st;
        cursor4[i4] = st;
    }
}

__global__ __launch_bounds__(256) void fill_kernel(
    const int* __restrict__ in_idx, const int* __restrict__ out_idx,
    u32* __restrict__ cursor, u32* __restrict__ sorted)
{
    __shared__ u32 lh[NCHUNK];
    __shared__ u32 lbase[NCHUNK];
    const int k    = blockIdx.y;
    const int base = blockIdx.x * RPH;

    for (int t = threadIdx.x; t < NCHUNK; t += 256) lh[t] = 0;
    __syncthreads();
    for (int r = base + threadIdx.x; r < base + RPH; r += 256)
        atomicAdd(&lh[((u32)out_idx[(size_t)k * R_RULES + r]) >> CH_SHIFT], 1u);
    __syncthreads();
    for (int t = threadIdx.x; t < NCHUNK; t += 256) {
        u32 v = lh[t];
        if (v) lbase[t] = atomicAdd(&cursor[(u32)t * K_OFF + (u32)k], v);
    }
    __syncthreads();
    for (int t = threadIdx.x; t < NCHUNK; t += 256) lh[t] = 0;
    __syncthreads();
    for (int r = base + threadIdx.x; r < base + RPH; r += 256) {
        u32 o  = (u32)out_idx[(size_t)k * R_RULES + r];
        u32 iv = (u32)in_idx[(size_t)k * R_RULES + r];
        u32 ch = o >> CH_SHIFT;
        u32 off = atomicAdd(&lh[ch], 1u);
        sorted[lbase[ch] + off] =
            ((o & (u32)(CH_ROWS - 1)) << 24) | ((u32)k << 19) | iv;
    }
}

// ===========================================================================
// gather: block = chunk; contiguous entry range [start[ch*27], start[ch*27+27]).
// 8 groups x 32 lanes, channel = lane (wcol = 32 VGPRs, truly resident).
// Equal static slices per group. 2-deep ping-pong prefetch of entry + feat row.
// ds_add_f32 into 128x33 LDS accumulator. Zero global atomics.
// ===========================================================================
#define LOADROW(f, entry) { \
    const float4* _p = reinterpret_cast<const float4*>(feat + (size_t)((entry) & 0x7FFFFu) * NC); \
    _Pragma("unroll") \
    for (int _q = 0; _q < 8; ++_q) f[_q] = _p[_q]; }

#define COMPUTE(entry, f) { \
    const int _k = (int)(((entry) >> 19) & 31u); \
    if (_k != curk) { \
        curk = _k; \
        const float* _w = weight + (size_t)_k * NC * NC + c; \
        _Pragma("unroll") \
        for (int _i = 0; _i < NC; ++_i) wcol[_i] = _w[(size_t)_i * NC]; \
    } \
    float _a0 = 0.f, _a1 = 0.f, _a2 = 0.f, _a3 = 0.f; \
    _Pragma("unroll") \
    for (int _q = 0; _q < 8; ++_q) { \
        _a0 += f[_q].x * wcol[4*_q+0]; \
        _a1 += f[_q].y * wcol[4*_q+1]; \
        _a2 += f[_q].z * wcol[4*_q+2]; \
        _a3 += f[_q].w * wcol[4*_q+3]; \
    } \
    atomicAdd(&acc[(int)((entry) >> 24) * 33 + c], (_a0 + _a1) + (_a2 + _a3)); }

__global__ __launch_bounds__(256, 4) void gather_kernel(
    const float* __restrict__ feat,    // [N_IN, 32]
    const float* __restrict__ weight,  // [27*32, 32]
    const u32*   __restrict__ sorted,  // [TOTAL_E]
    const u32*   __restrict__ start,   // [NB_PAD]
    const float* __restrict__ bias,
    float*       __restrict__ out)     // [N_OUT, 32]
{
    __shared__ float acc[CH_ROWS * 33];
    for (int t = threadIdx.x; t < CH_ROWS * 33; t += 256) acc[t] = 0.0f;
    __syncthreads();

    const int chunk = blockIdx.x;
    const int c = threadIdx.x & 31;     // channel = lane
    const int g = threadIdx.x >> 5;     // group 0..7

    const u32 s = start[(u32)chunk * K_OFF];
    const u32 e = start[(u32)chunk * K_OFF + K_OFF];
    const u32 len = e - s;
    const u32 per = (len + 7) >> 3;
    u32 idx  = s + (u32)g * per;
    u32 iend = idx + per;
    if (iend > e) iend = e;

    float wcol[NC];
    int curk = -1;

    if (idx < iend) {
        u32 eA = sorted[idx];
        float4 fA[8];
        LOADROW(fA, eA);
        while (true) {
            u32 eB = 0;
            float4 fB[8];
            const bool hasB = (idx + 1 < iend);
            if (hasB) { eB = sorted[idx + 1]; LOADROW(fB, eB); }
            COMPUTE(eA, fA);
            if (!hasB) break;
            const bool hasA2 = (idx + 2 < iend);
            if (hasA2) { eA = sorted[idx + 2]; LOADROW(fA, eA); }
            COMPUTE(eB, fB);
            if (!hasA2) break;
            idx += 2;
        }
    }
    __syncthreads();

    const int obase = chunk << CH_SHIFT;
    for (int t = threadIdx.x; t < CH_ROWS * NC; t += 256) {
        const int o = obase + (t >> 5), cc = t & 31;
        if (o < N_OUT_SZ)
            out[(size_t)o * NC + cc] = acc[(t >> 5) * 33 + cc] + bias[cc];
    }
}

// ===========================================================================
// Fallback paths (R4 pk-f16 atomics; R2 f32 atomics)
// ===========================================================================
__global__ __launch_bounds__(256) void zero_ws_kernel(uint4* __restrict__ ws)
{
    const int total = ACC_WORDS / 4;
    int idx = blockIdx.x * 256 + threadIdx.x;
    if (idx < total) ws[idx] = make_uint4(0, 0, 0, 0);
}

__global__ __launch_bounds__(256) void conv_scatter_f16_kernel(
    const float* __restrict__ feat, const float* __restrict__ weight,
    const int* __restrict__ in_idx, const int* __restrict__ out_idx,
    __half2* __restrict__ acc)
{
    __shared__ float2 Wlds[NC * 16];
    const int k = blockIdx.y;
    const float2* wg = reinterpret_cast<const float2*>(weight + k * NC * NC);
    for (int t = threadIdx.x; t < NC * 16; t += 256)
        Wlds[t] = wg[t];
    __syncthreads();
    const int j = threadIdx.x & 15;
    const int g = threadIdx.x >> 4;
    float2 wcol[NC];
#pragma unroll
    for (int i = 0; i < NC; ++i) wcol[i] = Wlds[i * 16 + j];
    const int rbase = blockIdx.x * 64;
    for (int rr = g; rr < 64; rr += 16) {
        const int r = rbase + rr;
        const int irow = in_idx[(size_t)k * R_RULES + r];
        const int orow = out_idx[(size_t)k * R_RULES + r];
        const float4* fv = reinterpret_cast<const float4*>(feat + (size_t)irow * NC);
        float a0 = 0.0f, a1 = 0.0f;
#pragma unroll
        for (int i0 = 0; i0 < 8; ++i0) {
            const float4 f = fv[i0];
            a0 += f.x * wcol[i0*4+0].x;  a1 += f.x * wcol[i0*4+0].y;
            a0 += f.y * wcol[i0*4+1].x;  a1 += f.y * wcol[i0*4+1].y;
            a0 += f.z * wcol[i0*4+2].x;  a1 += f.z * wcol[i0*4+2].y;
            a0 += f.w * wcol[i0*4+3].x;  a1 += f.w * wcol[i0*4+3].y;
        }
        unsafeAtomicAdd(acc + (size_t)orow * 16 + j, __floats2half2_rn(a0, a1));
    }
}

__global__ __launch_bounds__(256) void unpack_kernel(
    const __half2* __restrict__ acc, const float* __restrict__ bias,
    float* __restrict__ out)
{
    int t = blockIdx.x * 256 + threadIdx.x;
    if (t >= ACC_WORDS) return;
    const int j = t & 15;
    const float2 v = __half22float2(acc[t]);
    const float2 b = reinterpret_cast<const float2*>(bias)[j];
    float2 o; o.x = v.x + b.x; o.y = v.y + b.y;
    reinterpret_cast<float2*>(out)[t] = o;
}

__global__ __launch_bounds__(256) void init_out_kernel(
    const float* __restrict__ bias, float* __restrict__ out)
{
    int idx = blockIdx.x * 256 + threadIdx.x;
    const int total4 = N_OUT_SZ * NC / 4;
    if (idx >= total4) return;
    int c0 = (idx * 4) & (NC - 1);
    float4 b;
    b.x = bias[c0+0]; b.y = bias[c0+1]; b.z = bias[c0+2]; b.w = bias[c0+3];
    reinterpret_cast<float4*>(out)[idx] = b;
}

__global__ __launch_bounds__(256) void conv_scatter_kernel(
    const float* __restrict__ feat, const float* __restrict__ weight,
    const int* __restrict__ in_idx, const int* __restrict__ out_idx,
    float* __restrict__ out)
{
    __shared__ float Wlds[NC * NC];
    const int k  = blockIdx.y;
    const int c  = threadIdx.x & (NC - 1);
    const int rg = threadIdx.x >> 5;
    for (int t = threadIdx.x; t < NC * NC; t += 256)
        Wlds[t] = weight[k * NC * NC + t];
    __syncthreads();
    float wcol[NC];
#pragma unroll
    for (int i = 0; i < NC; ++i) wcol[i] = Wlds[i * NC + c];
    const int rbase = blockIdx.x * 64;
    for (int rr = rg; rr < 64; rr += 8) {
        const int r = rbase + rr;
        const int irow = in_idx[(size_t)k * R_RULES + r];
        const int orow = out_idx[(size_t)k * R_RULES + r];
        const float4* fv = reinterpret_cast<const float4*>(feat + (size_t)irow * NC);
        float acc = 0.0f;
#pragma unroll
        for (int i0 = 0; i0 < 8; ++i0) {
            const float4 f = fv[i0];
            acc += f.x * wcol[i0*4+0];
            acc += f.y * wcol[i0*4+1];
            acc += f.z * wcol[i0*4+2];
            acc += f.w * wcol[i0*4+3];
        }
        atomicAdd(out + (size_t)orow * NC + c, acc);
    }
}

// ---------------------------------------------------------------------------
extern "C" void kernel_launch(void* const* d_in, const int* in_sizes, int n_in,
                              void* d_out, int out_size, void* d_ws, size_t ws_size,
                              hipStream_t stream)
{
    const float* feat    = (const float*)d_in[0];
    const float* weight  = (const float*)d_in[1];
    const float* bias    = (const float*)d_in[2];
    const int*   in_idx  = (const int*)d_in[3];
    const int*   out_idx = (const int*)d_in[4];
    float*       out     = (float*)d_out;

    if (ws_size >= WS_NEW_NEEDED) {
        char* ws = (char*)d_ws;
        u32* sorted = (u32*)(ws + SORT_OFF);
        u32* cnt    = (u32*)(ws + CNT_OFF);
        u32* start  = (u32*)(ws + START_OFF);
        u32* cursor = (u32*)(ws + CURSOR_OFF);
        u32* bsum   = (u32*)(ws + BSUM_OFF);
        u32* boff   = (u32*)(ws + BOFF_OFF);

        zero_cnt_kernel<<<NSCANBLK, 256, 0, stream>>>((uint4*)cnt);
        {
            dim3 grid(HIST_BLK, K_OFF);
            hist_kernel<<<grid, 256, 0, stream>>>(out_idx, cnt);
        }
        blocksum_kernel<<<NSCANBLK, 256, 0, stream>>>((const uint4*)cnt, bsum);
        scanblk_kernel<<<1, 256, 0, stream>>>(bsum, boff);
        scanwrite_kernel<<<NSCANBLK, 256, 0, stream>>>(
            (const uint4*)cnt, boff, (uint4*)start, (uint4*)cursor);
        {
            dim3 grid(HIST_BLK, K_OFF);
            fill_kernel<<<grid, 256, 0, stream>>>(in_idx, out_idx, cursor, sorted);
        }
        gather_kernel<<<NCHUNK, 256, 0, stream>>>(feat, weight, sorted, start, bias, out);
    } else if (ws_size >= WS_F16_NEEDED) {
        __half2* acc = (__half2*)d_ws;
        zero_ws_kernel<<<(ACC_WORDS / 4 + 255) / 256, 256, 0, stream>>>((uint4*)d_ws);
        dim3 grid(R_RULES / 64, K_OFF);
        conv_scatter_f16_kernel<<<grid, 256, 0, stream>>>(feat, weight, in_idx, out_idx, acc);
        unpack_kernel<<<ACC_WORDS / 256, 256, 0, stream>>>(acc, bias, out);
    } else {
        int total4 = N_OUT_SZ * NC / 4;
        init_out_kernel<<<(total4 + 255) / 256, 256, 0, stream>>>(bias, out);
        dim3 grid(R_RULES / 64, K_OFF);
        conv_scatter_kernel<<<grid, 256, 0, stream>>>(feat, weight, in_idx, out_idx, out);
    }
}

// Round 9
// 1095.312 us; speedup vs baseline: 1.1419x; 1.1419x over previous
//
#include <hip/hip_runtime.h>
#include <hip/hip_fp16.h>

#define N_IN_SZ   400000
#define N_OUT_SZ  200000
#define K_OFF     27
#define R_RULES   200000
#define NC        32
#define TOTAL_E   (K_OFF * R_RULES)     // 5,400,000

// chunk = o >> 6 (64 outputs per chunk); buckets chunk-major: b = chunk*27 + k
#define CH_SHIFT  6
#define CH_ROWS   64
#define NCHUNK    3125                   // 200000/64 exactly
#define NB        (NCHUNK * K_OFF)       // 84,375
#define NB_PAD    84992                  // 83*1024
#define N_CNT4    (NB_PAD / 4)           // 21,248
#define NSCANBLK  83                     // 83*256 == 21,248 exactly

#define HIST_BLK  8
#define RPH       25000                  // rules per hist/fill block

typedef unsigned int u32;
typedef unsigned long long u64;

// ---------------- ws layout (bytes) ----------------
// sorted : u32[TOTAL_E]  = 21,600,000
// A      : u32[NB_PAD]   =    339,968   (counts -> starts -> ends, in place)
// bsum   : u32[256]      =      1,024
// boff   : u32[256]      =      1,024
#define SORT_OFF    0ull
#define A_OFF       21600000ull
#define BSUM_OFF    (A_OFF + (u64)NB_PAD * 4)      // 21,939,968
#define BOFF_OFF    (BSUM_OFF + 1024ull)
#define WS_NEW_NEEDED (BOFF_OFF + 1024ull)         // 21,942,016 < 22,116,608 (known fit)

// fallback (R4) ws need
#define ACC_WORDS  (N_OUT_SZ * 16)
#define WS_F16_NEEDED  ((size_t)ACC_WORDS * 4)

// ===========================================================================
// sort pipeline. entry = (o&63)<<24 | k<<19 | irow   (irow < 2^19)
// ===========================================================================
__global__ __launch_bounds__(256) void zero_cnt_kernel(uint4* __restrict__ A4)
{
    int i = blockIdx.x * 256 + threadIdx.x;
    if (i < N_CNT4) A4[i] = make_uint4(0, 0, 0, 0);
}

__global__ __launch_bounds__(256) void hist_kernel(
    const int* __restrict__ out_idx, u32* __restrict__ A)
{
    __shared__ u32 lh[NCHUNK];
    for (int t = threadIdx.x; t < NCHUNK; t += 256) lh[t] = 0;
    __syncthreads();
    const int k    = blockIdx.y;
    const int base = blockIdx.x * RPH;
    for (int r = base + threadIdx.x; r < base + RPH; r += 256)
        atomicAdd(&lh[((u32)out_idx[(size_t)k * R_RULES + r]) >> CH_SHIFT], 1u);
    __syncthreads();
    for (int t = threadIdx.x; t < NCHUNK; t += 256) {
        u32 v = lh[t];
        if (v) atomicAdd(&A[(u32)t * K_OFF + (u32)k], v);
    }
}

__global__ __launch_bounds__(256) void blocksum_kernel(
    const uint4* __restrict__ A4, u32* __restrict__ bsum)
{
    int i4 = blockIdx.x * 256 + threadIdx.x;
    uint4 c = A4[i4];                      // grid covers N_CNT4 exactly
    u32 s = c.x + c.y + c.z + c.w;
    int lane = threadIdx.x & 63;
#pragma unroll
    for (int off = 32; off > 0; off >>= 1)
        s += __shfl_down(s, off);
    __shared__ u32 ws[4];
    int wid = threadIdx.x >> 6;
    if (lane == 0) ws[wid] = s;
    __syncthreads();
    if (threadIdx.x == 0)
        bsum[blockIdx.x] = ws[0] + ws[1] + ws[2] + ws[3];
}

__global__ __launch_bounds__(256) void scanblk_kernel(
    const u32* __restrict__ bsum, u32* __restrict__ boff)
{
    __shared__ u32 lds[NSCANBLK];
    int t = threadIdx.x;
    if (t < NSCANBLK) lds[t] = bsum[t];
    __syncthreads();
    if (t == 0) {
        u32 run = 0;
        for (int i = 0; i < NSCANBLK; ++i) { u32 v = lds[i]; lds[i] = run; run += v; }
    }
    __syncthreads();
    if (t < NSCANBLK) boff[t] = lds[t];
}

// in-place: A (counts) -> A (exclusive-prefix starts)
__global__ __launch_bounds__(256) void scanwrite_kernel(
    uint4* __restrict__ A4, const u32* __restrict__ boff)
{
    int i4 = blockIdx.x * 256 + threadIdx.x;
    uint4 c = A4[i4];
    u32 lsum = c.x + c.y + c.z + c.w;
    u32 s = lsum;
    int lane = threadIdx.x & 63;
#pragma unroll
    for (int off = 1; off < 64; off <<= 1) {
        u32 v = __shfl_up(s, off);
        if (lane >= off) s += v;
    }
    __shared__ u32 wsum[4], wbase[4];
    int wid = threadIdx.x >> 6;
    if (lane == 63) wsum[wid] = s;
    __syncthreads();
    if (threadIdx.x == 0) {
        u32 run = 0;
        for (int w = 0; w < 4; ++w) { wbase[w] = run; run += wsum[w]; }
    }
    __syncthreads();
    u32 base = boff[blockIdx.x] + wbase[wid] + (s - lsum);
    uint4 st;
    st.x = base;
    st.y = st.x + c.x;
    st.z = st.y + c.y;
    st.w = st.z + c.z;
    A4[i4] = st;
}

// fill: LDS hist -> reserve base (atomicAdd on A, leaves A[b]=end_b) -> write
__global__ __launch_bounds__(256) void fill_kernel(
    const int* __restrict__ in_idx, const int* __restrict__ out_idx,
    u32* __restrict__ A, u32* __restrict__ sorted)
{
    __shared__ u32 lh[NCHUNK];
    __shared__ u32 lbase[NCHUNK];
    const int k    = blockIdx.y;
    const int base = blockIdx.x * RPH;

    for (int t = threadIdx.x; t < NCHUNK; t += 256) lh[t] = 0;
    __syncthreads();
    for (int r = base + threadIdx.x; r < base + RPH; r += 256)
        atomicAdd(&lh[((u32)out_idx[(size_t)k * R_RULES + r]) >> CH_SHIFT], 1u);
    __syncthreads();
    for (int t = threadIdx.x; t < NCHUNK; t += 256) {
        u32 v = lh[t];
        if (v) lbase[t] = atomicAdd(&A[(u32)t * K_OFF + (u32)k], v);
    }
    __syncthreads();
    for (int t = threadIdx.x; t < NCHUNK; t += 256) lh[t] = 0;
    __syncthreads();
    for (int r = base + threadIdx.x; r < base + RPH; r += 256) {
        u32 o  = (u32)out_idx[(size_t)k * R_RULES + r];
        u32 iv = (u32)in_idx[(size_t)k * R_RULES + r];
        u32 ch = o >> CH_SHIFT;
        u32 off = atomicAdd(&lh[ch], 1u);
        sorted[lbase[ch] + off] =
            ((o & (u32)(CH_ROWS - 1)) << 24) | ((u32)k << 19) | iv;
    }
}

// ===========================================================================
// gather: block = 64-row chunk; contiguous range [A[ch*27-1] (or 0), A[ch*27+26]).
// 16 groups x 16 lanes, lane = channel-pair (wcol = float2[32]); wave keeps
// 4 entries in flight. ds_add_f32 into 64x33 LDS acc. Zero global atomics.
// ===========================================================================
__global__ __launch_bounds__(256, 4) void gather_kernel(
    const float* __restrict__ feat,    // [N_IN, 32]
    const float* __restrict__ weight,  // [27*32, 32]
    const u32*   __restrict__ sorted,  // [TOTAL_E]
    const u32*   __restrict__ A,       // post-fill: A[b] = end_b
    const float* __restrict__ bias,
    float*       __restrict__ out)     // [N_OUT, 32]
{
    __shared__ float acc[CH_ROWS * 33];
    for (int t = threadIdx.x; t < CH_ROWS * 33; t += 256) acc[t] = 0.0f;
    __syncthreads();

    const int chunk = blockIdx.x;
    const int j = threadIdx.x & 15;     // channel pair (2j, 2j+1)
    const int g = threadIdx.x >> 4;     // group 0..15

    const u32 s = (chunk > 0) ? A[(u32)chunk * K_OFF - 1] : 0u;
    const u32 e = A[(u32)chunk * K_OFF + (K_OFF - 1)];
    const u32 len = e - s;
    const u32 per = (len + 15) >> 4;
    u32 idx  = s + (u32)g * per;
    u32 iend = idx + per;
    if (iend > e) iend = e;

    float2 wcol[NC];
    int curk = -1;

    if (idx < iend) {
        u32 ent = sorted[idx];
        while (true) {
            const bool more = (idx + 1 < iend);
            u32 nxt = 0;
            if (more) nxt = sorted[idx + 1];          // prefetch entry word

            const int k = (int)((ent >> 19) & 31u);
            if (k != curk) {
                curk = k;
                const float2* w = reinterpret_cast<const float2*>(
                    weight + (size_t)k * NC * NC) + j;
#pragma unroll
                for (int i = 0; i < NC; ++i)
                    wcol[i] = w[(size_t)i * 16];
            }

            const float4* p = reinterpret_cast<const float4*>(
                feat + (size_t)(ent & 0x7FFFFu) * NC);
            float4 q0 = p[0], q1 = p[1], q2 = p[2], q3 = p[3];
            float4 q4 = p[4], q5 = p[5], q6 = p[6], q7 = p[7];

            float a0 = 0.f, a1 = 0.f;
            a0 += q0.x*wcol[ 0].x; a1 += q0.x*wcol[ 0].y;
            a0 += q0.y*wcol[ 1].x; a1 += q0.y*wcol[ 1].y;
            a0 += q0.z*wcol[ 2].x; a1 += q0.z*wcol[ 2].y;
            a0 += q0.w*wcol[ 3].x; a1 += q0.w*wcol[ 3].y;
            a0 += q1.x*wcol[ 4].x; a1 += q1.x*wcol[ 4].y;
            a0 += q1.y*wcol[ 5].x; a1 += q1.y*wcol[ 5].y;
            a0 += q1.z*wcol[ 6].x; a1 += q1.z*wcol[ 6].y;
            a0 += q1.w*wcol[ 7].x; a1 += q1.w*wcol[ 7].y;
            a0 += q2.x*wcol[ 8].x; a1 += q2.x*wcol[ 8].y;
            a0 += q2.y*wcol[ 9].x; a1 += q2.y*wcol[ 9].y;
            a0 += q2.z*wcol[10].x; a1 += q2.z*wcol[10].y;
            a0 += q2.w*wcol[11].x; a1 += q2.w*wcol[11].y;
            a0 += q3.x*wcol[12].x; a1 += q3.x*wcol[12].y;
            a0 += q3.y*wcol[13].x; a1 += q3.y*wcol[13].y;
            a0 += q3.z*wcol[14].x; a1 += q3.z*wcol[14].y;
            a0 += q3.w*wcol[15].x; a1 += q3.w*wcol[15].y;
            a0 += q4.x*wcol[16].x; a1 += q4.x*wcol[16].y;
            a0 += q4.y*wcol[17].x; a1 += q4.y*wcol[17].y;
            a0 += q4.z*wcol[18].x; a1 += q4.z*wcol[18].y;
            a0 += q4.w*wcol[19].x; a1 += q4.w*wcol[19].y;
            a0 += q5.x*wcol[20].x; a1 += q5.x*wcol[20].y;
            a0 += q5.y*wcol[21].x; a1 += q5.y*wcol[21].y;
            a0 += q5.z*wcol[22].x; a1 += q5.z*wcol[22].y;
            a0 += q5.w*wcol[23].x; a1 += q5.w*wcol[23].y;
            a0 += q6.x*wcol[24].x; a1 += q6.x*wcol[24].y;
            a0 += q6.y*wcol[25].x; a1 += q6.y*wcol[25].y;
            a0 += q6.z*wcol[26].x; a1 += q6.z*wcol[26].y;
            a0 += q6.w*wcol[27].x; a1 += q6.w*wcol[27].y;
            a0 += q7.x*wcol[28].x; a1 += q7.x*wcol[28].y;
            a0 += q7.y*wcol[29].x; a1 += q7.y*wcol[29].y;
            a0 += q7.z*wcol[30].x; a1 += q7.z*wcol[30].y;
            a0 += q7.w*wcol[31].x; a1 += q7.w*wcol[31].y;

            const int ol = (int)(ent >> 24);
            atomicAdd(&acc[ol * 33 + 2 * j    ], a0);   // ds_add_f32 (no return)
            atomicAdd(&acc[ol * 33 + 2 * j + 1], a1);

            if (!more) break;
            ent = nxt;
            ++idx;
        }
    }
    __syncthreads();

    const int obase = chunk << CH_SHIFT;                // 3125*64 = 200000 exact
    for (int t = threadIdx.x; t < CH_ROWS * NC; t += 256) {
        const int o = t >> 5, c = t & 31;
        out[(size_t)(obase + o) * NC + c] = acc[o * 33 + c] + bias[c];
    }
}

// ===========================================================================
// Fallback paths (R4 pk-f16 atomics; R2 f32 atomics)
// ===========================================================================
__global__ __launch_bounds__(256) void zero_ws_kernel(uint4* __restrict__ ws)
{
    const int total = ACC_WORDS / 4;
    int idx = blockIdx.x * 256 + threadIdx.x;
    if (idx < total) ws[idx] = make_uint4(0, 0, 0, 0);
}

__global__ __launch_bounds__(256) void conv_scatter_f16_kernel(
    const float* __restrict__ feat, const float* __restrict__ weight,
    const int* __restrict__ in_idx, const int* __restrict__ out_idx,
    __half2* __restrict__ acc)
{
    __shared__ float2 Wlds[NC * 16];
    const int k = blockIdx.y;
    const float2* wg = reinterpret_cast<const float2*>(weight + k * NC * NC);
    for (int t = threadIdx.x; t < NC * 16; t += 256)
        Wlds[t] = wg[t];
    __syncthreads();
    const int j = threadIdx.x & 15;
    const int g = threadIdx.x >> 4;
    float2 wcol[NC];
#pragma unroll
    for (int i = 0; i < NC; ++i) wcol[i] = Wlds[i * 16 + j];
    const int rbase = blockIdx.x * 64;
    for (int rr = g; rr < 64; rr += 16) {
        const int r = rbase + rr;
        const int irow = in_idx[(size_t)k * R_RULES + r];
        const int orow = out_idx[(size_t)k * R_RULES + r];
        const float4* fv = reinterpret_cast<const float4*>(feat + (size_t)irow * NC);
        float a0 = 0.0f, a1 = 0.0f;
#pragma unroll
        for (int i0 = 0; i0 < 8; ++i0) {
            const float4 f = fv[i0];
            a0 += f.x * wcol[i0*4+0].x;  a1 += f.x * wcol[i0*4+0].y;
            a0 += f.y * wcol[i0*4+1].x;  a1 += f.y * wcol[i0*4+1].y;
            a0 += f.z * wcol[i0*4+2].x;  a1 += f.z * wcol[i0*4+2].y;
            a0 += f.w * wcol[i0*4+3].x;  a1 += f.w * wcol[i0*4+3].y;
        }
        unsafeAtomicAdd(acc + (size_t)orow * 16 + j, __floats2half2_rn(a0, a1));
    }
}

__global__ __launch_bounds__(256) void unpack_kernel(
    const __half2* __restrict__ acc, const float* __restrict__ bias,
    float* __restrict__ out)
{
    int t = blockIdx.x * 256 + threadIdx.x;
    if (t >= ACC_WORDS) return;
    const int j = t & 15;
    const float2 v = __half22float2(acc[t]);
    const float2 b = reinterpret_cast<const float2*>(bias)[j];
    float2 o; o.x = v.x + b.x; o.y = v.y + b.y;
    reinterpret_cast<float2*>(out)[t] = o;
}

__global__ __launch_bounds__(256) void init_out_kernel(
    const float* __restrict__ bias, float* __restrict__ out)
{
    int idx = blockIdx.x * 256 + threadIdx.x;
    const int total4 = N_OUT_SZ * NC / 4;
    if (idx >= total4) return;
    int c0 = (idx * 4) & (NC - 1);
    float4 b;
    b.x = bias[c0+0]; b.y = bias[c0+1]; b.z = bias[c0+2]; b.w = bias[c0+3];
    reinterpret_cast<float4*>(out)[idx] = b;
}

__global__ __launch_bounds__(256) void conv_scatter_kernel(
    const float* __restrict__ feat, const float* __restrict__ weight,
    const int* __restrict__ in_idx, const int* __restrict__ out_idx,
    float* __restrict__ out)
{
    __shared__ float Wlds[NC * NC];
    const int k  = blockIdx.y;
    const int c  = threadIdx.x & (NC - 1);
    const int rg = threadIdx.x >> 5;
    for (int t = threadIdx.x; t < NC * NC; t += 256)
        Wlds[t] = weight[k * NC * NC + t];
    __syncthreads();
    float wcol[NC];
#pragma unroll
    for (int i = 0; i < NC; ++i) wcol[i] = Wlds[i * NC + c];
    const int rbase = blockIdx.x * 64;
    for (int rr = rg; rr < 64; rr += 8) {
        const int r = rbase + rr;
        const int irow = in_idx[(size_t)k * R_RULES + r];
        const int orow = out_idx[(size_t)k * R_RULES + r];
        const float4* fv = reinterpret_cast<const float4*>(feat + (size_t)irow * NC);
        float acc = 0.0f;
#pragma unroll
        for (int i0 = 0; i0 < 8; ++i0) {
            const float4 f = fv[i0];
            acc += f.x * wcol[i0*4+0];
            acc += f.y * wcol[i0*4+1];
            acc += f.z * wcol[i0*4+2];
            acc += f.w * wcol[i0*4+3];
        }
        atomicAdd(out + (size_t)orow * NC + c, acc);
    }
}

// ---------------------------------------------------------------------------
extern "C" void kernel_launch(void* const* d_in, const int* in_sizes, int n_in,
                              void* d_out, int out_size, void* d_ws, size_t ws_size,
                              hipStream_t stream)
{
    const float* feat    = (const float*)d_in[0];
    const float* weight  = (const float*)d_in[1];
    const float* bias    = (const float*)d_in[2];
    const int*   in_idx  = (const int*)d_in[3];
    const int*   out_idx = (const int*)d_in[4];
    float*       out     = (float*)d_out;

    if (ws_size >= WS_NEW_NEEDED) {
        char* ws = (char*)d_ws;
        u32* sorted = (u32*)(ws + SORT_OFF);
        u32* A      = (u32*)(ws + A_OFF);
        u32* bsum   = (u32*)(ws + BSUM_OFF);
        u32* boff   = (u32*)(ws + BOFF_OFF);

        zero_cnt_kernel<<<NSCANBLK, 256, 0, stream>>>((uint4*)A);
        {
            dim3 grid(HIST_BLK, K_OFF);
            hist_kernel<<<grid, 256, 0, stream>>>(out_idx, A);
        }
        blocksum_kernel<<<NSCANBLK, 256, 0, stream>>>((const uint4*)A, bsum);
        scanblk_kernel<<<1, 256, 0, stream>>>(bsum, boff);
        scanwrite_kernel<<<NSCANBLK, 256, 0, stream>>>((uint4*)A, boff);
        {
            dim3 grid(HIST_BLK, K_OFF);
            fill_kernel<<<grid, 256, 0, stream>>>(in_idx, out_idx, A, sorted);
        }
        gather_kernel<<<NCHUNK, 256, 0, stream>>>(feat, weight, sorted, A, bias, out);
    } else if (ws_size >= WS_F16_NEEDED) {
        __half2* acc = (__half2*)d_ws;
        zero_ws_kernel<<<(ACC_WORDS / 4 + 255) / 256, 256, 0, stream>>>((uint4*)d_ws);
        dim3 grid(R_RULES / 64, K_OFF);
        conv_scatter_f16_kernel<<<grid, 256, 0, stream>>>(feat, weight, in_idx, out_idx, acc);
        unpack_kernel<<<ACC_WORDS / 256, 256, 0, stream>>>(acc, bias, out);
    } else {
        int total4 = N_OUT_SZ * NC / 4;
        init_out_kernel<<<(total4 + 255) / 256, 256, 0, stream>>>(bias, out);
        dim3 grid(R_RULES / 64, K_OFF);
        conv_scatter_kernel<<<grid, 256, 0, stream>>>(feat, weight, in_idx, out_idx, out);
    }
}